// Round 1
// baseline (119.105 us; speedup 1.0000x reference)
//
#include <hip/hip_runtime.h>
#include <math.h>

// Problem constants (from reference)
#define BATCH 32
#define NGT   50
#define ATOT  10710   // 68*120 + 34*60 + 17*30
#define NCH   16      // 5 + 11 classes
// level boundaries
#define L0_END 8160   // 68*120
#define L1_END 10200  // + 34*60

__global__ __launch_bounds__(256) void simota_fused_kernel(
    const float* __restrict__ preds,    // (B, A, 16)
    const float* __restrict__ labels,   // (B, G, 5)  [cls, cx, cy, w, h]
    float* __restrict__ out_decoded,    // (B, A, 16)
    float* __restrict__ out_fg,         // (B, A)
    float* __restrict__ out_ibc)        // (B, G, A)
{
    const int b   = blockIdx.y;
    const int a   = blockIdx.x * blockDim.x + threadIdx.x;
    const int tid = threadIdx.x;

    // Stage per-batch GT boxes: precompute box edges and validity.
    __shared__ float s_gx[NGT], s_gy[NGT];
    __shared__ float s_xlo[NGT], s_xhi[NGT], s_ylo[NGT], s_yhi[NGT];
    __shared__ int   s_valid[NGT];
    if (tid < NGT) {
        const float* lr = labels + ((size_t)b * NGT + tid) * 5;
        float l0 = lr[0], gx = lr[1], gy = lr[2], gw = lr[3], gh = lr[4];
        // valid = sum(labels, axis=2) > 0
        float sum = l0 + gx + gy + gw + gh;
        s_valid[tid] = (sum > 0.0f) ? 1 : 0;
        float hw = 0.5f * gw;   // exact
        float hh = 0.5f * gh;   // exact
        s_gx[tid]  = gx;        s_gy[tid]  = gy;
        s_xlo[tid] = gx - hw;   s_xhi[tid] = gx + hw;
        s_ylo[tid] = gy - hh;   s_yhi[tid] = gy + hh;
    }
    __syncthreads();
    if (a >= ATOT) return;

    // Per-anchor grid coords + stride (row-major within each level: idx = y*w + x)
    int w, la; float s;
    if (a < L0_END)      { w = 120; s = 8.0f;  la = a; }
    else if (a < L1_END) { w = 60;  s = 16.0f; la = a - L0_END; }
    else                 { w = 30;  s = 32.0f; la = a - L1_END; }
    const float xg = (float)(la % w);
    const float yg = (float)(la / w);

    // ---- decode ----
    const float* p = preds + ((size_t)b * ATOT + a) * NCH;
    float4 p0 = ((const float4*)p)[0];
    float4 p1 = ((const float4*)p)[1];
    float4 p2 = ((const float4*)p)[2];
    float4 p3 = ((const float4*)p)[3];
    float4 d0;
    d0.x = (p0.x + xg) * s;    // exact mul by power-of-two stride
    d0.y = (p0.y + yg) * s;
    d0.z = expf(p0.z) * s;
    d0.w = expf(p0.w) * s;
    float* dptr = out_decoded + ((size_t)b * ATOT + a) * NCH;
    ((float4*)dptr)[0] = d0;
    ((float4*)dptr)[1] = p1;
    ((float4*)dptr)[2] = p2;
    ((float4*)dptr)[3] = p3;

    // ---- masks ----
    const float xc = (xg + 0.5f) * s;  // exact
    const float yc = (yg + 0.5f) * s;  // exact
    const float r  = 2.5f * s;         // exact (20 / 40 / 80)

    int fg = 0;
    float* ibc = out_ibc + (size_t)b * NGT * ATOT + a;
    #pragma unroll 10
    for (int g = 0; g < NGT; ++g) {
        const int   v  = s_valid[g];
        const float gx = s_gx[g], gy = s_gy[g];
        // in_box: min over 4 edge distances > 0
        float bx = fminf(xc - s_xlo[g], s_xhi[g] - xc);
        float by = fminf(yc - s_ylo[g], s_yhi[g] - yc);
        int in_box = ((fminf(bx, by) > 0.0f) ? 1 : 0) & v;
        // in_ctr: center-radius box
        float cx = fminf(xc - (gx - r), (gx + r) - xc);
        float cy = fminf(yc - (gy - r), (gy + r) - yc);
        int in_ctr = ((fminf(cx, cy) > 0.0f) ? 1 : 0) & v;
        fg |= (in_box | in_ctr);
        // in_box & in_ctr implies fg at this anchor -> fg_mask AND is redundant
        ibc[(size_t)g * ATOT] = (in_box & in_ctr) ? 1.0f : 0.0f;
    }
    out_fg[(size_t)b * ATOT + a] = fg ? 1.0f : 0.0f;
}

extern "C" void kernel_launch(void* const* d_in, const int* in_sizes, int n_in,
                              void* d_out, int out_size, void* d_ws, size_t ws_size,
                              hipStream_t stream) {
    const float* preds  = (const float*)d_in[0];  // (32, 10710, 16)
    const float* labels = (const float*)d_in[1];  // (32, 50, 5)
    float* out = (float*)d_out;
    // Flat output layout: decoded | fg_mask | in_box_and_ctr
    float* out_decoded = out;
    float* out_fg      = out + (size_t)BATCH * ATOT * NCH;                       // +5,483,520
    float* out_ibc     = out + (size_t)BATCH * ATOT * NCH + (size_t)BATCH * ATOT; // +342,720

    dim3 grid((ATOT + 255) / 256, BATCH);
    dim3 block(256);
    simota_fused_kernel<<<grid, block, 0, stream>>>(preds, labels, out_decoded, out_fg, out_ibc);
}